// Round 10
// baseline (6922.042 us; speedup 1.0000x reference)
//
#include <hip/hip_runtime.h>
#include <cstdint>
#include <cstddef>

// Problem constants (steps=30 is a fixed scalar input — hardcoded for a fixed
// graph-captured launch sequence).
#define B_DIM  1024
#define DIN    512
#define H_DIM  1024
#define DOUT   512
#define NB     10
#define STEPS  30

typedef _Float16 half_t;
typedef __attribute__((ext_vector_type(8))) _Float16 frag_ab;  // 8 fp16 in 4 VGPRs
typedef __attribute__((ext_vector_type(8))) _Float16 h8vec;
typedef __attribute__((ext_vector_type(4))) float    frag_cd;  // 4 fp32 acc

// async global->LDS, 16B per lane; LDS dest is wave-uniform base + lane*16
__device__ __forceinline__ void gload16(const void* g, void* l) {
    __builtin_amdgcn_global_load_lds(
        (const __attribute__((address_space(1))) void*)g,
        (__attribute__((address_space(3))) void*)l, 16, 0, 0);
}

// tanh via hardware exp2/rcp: tanh(x) = 1 - 2/(2^(2*log2e*x) + 1).
// ~5 VALU ops vs ~40-50 for library tanhf; |err| ~1e-6 (<< fp16 rounding);
// saturates correctly; NaN propagates.
__device__ __forceinline__ float fast_tanh(float x) {
    float e, r;
    asm("v_exp_f32 %0, %1" : "=v"(e) : "v"(x * 2.8853900817779268f));
    asm("v_rcp_f32 %0, %1" : "=v"(r) : "v"(e + 1.0f));
    return __builtin_fmaf(-2.0f, r, 1.0f);
}

// f32 -> f16 bulk convert (4 elements/thread)
__global__ void __launch_bounds__(256)
f2h_kernel(const float* __restrict__ src, half_t* __restrict__ dst, int n4)
{
    const int i = blockIdx.x * 256 + threadIdx.x;
    if (i < n4) {
        const float4 v = ((const float4*)src)[i];
        half_t o[4] = { (half_t)v.x, (half_t)v.y, (half_t)v.z, (half_t)v.w };
        ((uint2*)dst)[i] = *(const uint2*)o;
    }
}

// C = A(MxK,f16) @ W(NxK,f16)^T, fp32 acc.
// Round 10: 256x256 tile, 1024 thr / 16 waves (4x4), wave tile 64x64, BK=64,
// double-buffered 128KB dynamic LDS, 1 block/CU.
// Rationale (r9 pipe arithmetic): GEMM is LDS-read-BW-bound. Fragment bytes
// per CU scale inversely with wave-tile area: 64x32 wave = 0.75KB/MFMA
// (r9: 3.84MB/CU = ~19us at 85B/cyc, matches the 27us observed); 64x64 wave
// = 0.5KB/MFMA (2.56MB/CU = ~12.6us). 16 waves give 4 waves/SIMD TLP (r6's
// 64x64-wave config was latency-bound at 2/SIMD). 160 tiles = 160 blocks
// <= 256 CUs: one tile per CU, NO makespan quantization (r6-r9 were capped
// at 83% by 2.5 tiles/CU).
// Counted-vmcnt pipeline: stage(t+1) [4 loads/wave]; s_waitcnt vmcnt(4);
// barrier; compute(t) [32 MFMA/wave]; barrier.
//
// LDS XOR-swizzle (granule ^= row&7) via pre-swizzled global source
// (global_load_lds dest must stay linear) + matching XOR on fragment reads.
//
// Epilogue (MODE 1/2): two 128x256 passes; acc -> fsm (full 128KB as
// [128][256] f32) with granule swizzle gl=(g&56)|((g^(g>>3)^(row&7))&7),
// then a linear pass: 8 contiguous elems/thread, binp/A/aux as 16B vectors,
// one 16B store. ho re-read from global A (L2-warm).
//
// XCD mapping: n-chunked. 160 works, 20 per XCD (x-major w: bx=w&3,
// by=(w>>2)&3, n=w>>4) => XCD k owns ~1.25 layers; its W-slice (~2.5MB)
// persists in the 4MB private L2 across all dispatches.
//
// MODE 0: out32 = C + bias[col]                         (embed / head)
// MODE 1: out16 = 0.5*A[row,col] + 0.5*tanh(C+binp)     (inner iters 2,3,4; K==N)
// MODE 2: hn = 0.5*A[row,col] + 0.5*tanh(C+binp);
//         out16 = 0.5*aux16 + 0.5*hn   (iter 5 + outer mix; aux16==out16==h16)
template <int MODE>
__global__ void __launch_bounds__(1024, 4)
gemm_bt(const half_t* __restrict__ A,
        const half_t* __restrict__ W,
        const float* __restrict__ bias,
        const half_t* __restrict__ binp,
        const half_t* aux16,          // no restrict (aliases out16 in MODE 2)
        float* __restrict__ out32,
        half_t* out16,
        int M, int N, int K)
{
    // 128KB dynamic LDS: [0,64K) = lA[2][256*64] fp16, [64K,128K) = lB[2][...].
    // Epilogue reuses all of it as swizzled fsm[128][256] f32.
    extern __shared__ char smem[];
    half_t* lA  = (half_t*)smem;
    half_t* lB  = (half_t*)(smem + 65536);
    float*  fsm = (float*)smem;

    const int tid  = threadIdx.x;        // 0..1023
    const int wave = tid >> 6;           // 0..15
    const int lane = tid & 63;
    const int q    = lane >> 4;          // quad 0..3
    const int r16  = lane & 15;
    const int wm   = wave >> 2;          // 0..3: 64-row band
    const int wn   = wave & 3;           // 0..3: 64-col band

    // staging geometry (BK=64): lane i's 16B lands at lds_base + i*16.
    // phys slot (srow, lane&7); global column pre-swizzled so read-side XOR
    // (granule ^ row&7) recovers linear data.
    const int srow = lane >> 3;                     // 0..7 within 8-row chunk
    const int scol = ((lane & 7) ^ srow) * 8;       // swizzled k offset (elements)

    auto do_tile = [&](int bx, int by, int n) {
        const half_t* An = A + (size_t)n * M * K;
        const half_t* Wn = W + (size_t)n * N * K;
        const float*  bn = bias + (size_t)n * N;
        const half_t* binpn = binp;
        const half_t* auxn  = aux16;
        half_t* outn = out16;
        if (MODE != 0) {
            const size_t so = (size_t)n * M * N;
            binpn = binp + so;
            outn  = out16 + so;
            if (MODE == 2) auxn = aux16 + so;
        }
        const int tileM = by * 256;
        const int tileN = bx * 256;

        // per-lane global staging bases; each wave stages 16 rows of lA + lB
        const half_t* gA = An + (size_t)(tileM + wave * 16 + srow) * K + scol;
        const half_t* gW = Wn + (size_t)(tileN + wave * 16 + srow) * K + scol;

        auto stage = [&](int k0, int b) {
#pragma unroll
            for (int i = 0; i < 2; ++i) {
                gload16(gA + (size_t)i * 8 * K + k0,
                        (void*)&lA[b * 16384 + (wave * 16 + i * 8) * 64]);
                gload16(gW + (size_t)i * 8 * K + k0,
                        (void*)&lB[b * 16384 + (wave * 16 + i * 8) * 64]);
            }
        };

        frag_cd acc[4][4];
#pragma unroll
        for (int mt = 0; mt < 4; ++mt)
#pragma unroll
            for (int nt = 0; nt < 4; ++nt)
                acc[mt][nt] = (frag_cd){0.f, 0.f, 0.f, 0.f};

        const int NT = K >> 6;
        stage(0, 0);       // 4 loads/wave in flight

        int cur = 0;
        for (int t = 0; t < NT; ++t) {
            // prefetch next tile, then wait ONLY for tile t's 4 loads:
            // vmcnt counts in-order retirement; <=4 outstanding => 4 oldest done.
            if (t + 1 < NT) {
                stage((t + 1) << 6, cur ^ 1);                       // 8 in flight
                asm volatile("s_waitcnt vmcnt(4)" ::: "memory");    // t landed
            } else {
                asm volatile("s_waitcnt vmcnt(0)" ::: "memory");    // final tile
            }
            __builtin_amdgcn_s_barrier();   // all waves: buf[cur] resident
            asm volatile("" ::: "memory");

            frag_ab av[2][4], bv[2][4];
#pragma unroll
            for (int kk = 0; kk < 2; ++kk) {
                const int cb = ((kk * 4 + q) ^ (r16 & 7)) * 8;   // swizzled granule
#pragma unroll
                for (int mt = 0; mt < 4; ++mt)
                    av[kk][mt] = *(const frag_ab*)&lA[cur * 16384 + (wm * 64 + mt * 16 + r16) * 64 + cb];
#pragma unroll
                for (int nt = 0; nt < 4; ++nt)
                    bv[kk][nt] = *(const frag_ab*)&lB[cur * 16384 + (wn * 64 + nt * 16 + r16) * 64 + cb];
            }
#pragma unroll
            for (int kk = 0; kk < 2; ++kk)
#pragma unroll
                for (int mt = 0; mt < 4; ++mt)
#pragma unroll
                    for (int nt = 0; nt < 4; ++nt)
                        acc[mt][nt] = __builtin_amdgcn_mfma_f32_16x16x32_f16(
                            av[kk][mt], bv[kk][nt], acc[mt][nt], 0, 0, 0);

            asm volatile("" ::: "memory");
            __builtin_amdgcn_s_barrier();   // buf[cur] free for overwrite
            cur ^= 1;
        }

        // ---- epilogue ----  C/D layout: col = lane&15, row = quad*4 + reg
        if (MODE == 0) {
#pragma unroll
            for (int mt = 0; mt < 4; ++mt)
#pragma unroll
                for (int nt = 0; nt < 4; ++nt)
#pragma unroll
                    for (int r = 0; r < 4; ++r) {
                        const int row = tileM + wm * 64 + mt * 16 + q * 4 + r;
                        const int col = tileN + wn * 64 + nt * 16 + r16;
                        out32[(size_t)row * N + col] = acc[mt][nt][r] + bn[col];
                    }
            return;
        }

        // Two passes over 128-row halves; waves with (wm>>1)==pass own them.
        for (int pass = 0; pass < 2; ++pass) {
            __syncthreads();   // staging dead / previous pass-2 reads done
            if ((wm >> 1) == pass) {
#pragma unroll
                for (int mt = 0; mt < 4; ++mt)
#pragma unroll
                    for (int nt = 0; nt < 4; ++nt)
#pragma unroll
                        for (int r = 0; r < 4; ++r) {
                            const int rl  = (wm & 1) * 64 + mt * 16 + q * 4 + r; // 0..127
                            const int col = wn * 64 + nt * 16 + r16;             // 0..255
                            const int g   = col >> 2;                            // 0..63
                            const int gl  = (g & 56) | ((g ^ (g >> 3) ^ (rl & 7)) & 7);
                            fsm[rl * 256 + gl * 4 + (col & 3)] = acc[mt][nt][r];
                        }
            }
            __syncthreads();

            // linear vectorized pass: 8 contiguous elems/thread, 4 rounds
#pragma unroll
            for (int c = 0; c < 4; ++c) {
                const int e   = (c * 1024 + tid) * 8;   // elem idx in 128x256 half
                const int rl  = e >> 8;                 // 0..127
                const int cl  = e & 255;
                const int row = tileM + pass * 128 + rl;
                const int col = tileN + cl;
                const size_t gidx = (size_t)row * N + col;

                const int g0  = cl >> 2;
                const int gl0 = (g0 & 56) | ((g0 ^ (g0 >> 3) ^ (rl & 7)) & 7);
                const int g1  = g0 + 1;
                const int gl1 = (g1 & 56) | ((g1 ^ (g1 >> 3) ^ (rl & 7)) & 7);
                const float4 va = *(const float4*)&fsm[rl * 256 + gl0 * 4];
                const float4 vb = *(const float4*)&fsm[rl * 256 + gl1 * 4];
                const float vv[8] = {va.x, va.y, va.z, va.w, vb.x, vb.y, vb.z, vb.w};

                const h8vec bi8 = *(const h8vec*)&binpn[gidx];
                h8vec ho8, ax8;
                ho8 = *(const h8vec*)&An[(size_t)row * K + col];
                if (MODE == 2) ax8 = *(const h8vec*)&auxn[gidx];

                half_t o[8];
#pragma unroll
                for (int j = 0; j < 8; ++j) {
                    const float bi = (float)bi8[j];
                    const float tt = fast_tanh(vv[j] + bi);
                    const float ho = (float)ho8[j];
                    const float hn = 0.5f * ho + 0.5f * tt;
                    const float ov = (MODE == 2) ? 0.5f * (float)ax8[j] + 0.5f * hn : hn;
                    o[j] = (half_t)ov;
                }
                *(uint4*)&outn[gidx] = *(const uint4*)o;
            }
        }
    };

    if (MODE == 0) {
        // small dispatches (embed/head): bijective n-chunked swizzle on dim3 grid
        const int gx  = gridDim.x, gy = gridDim.y;
        const int nwg = gx * gy * gridDim.z;     // 16 or 8 — divisible by 8
        const int f   = blockIdx.x + gx * (blockIdx.y + gy * blockIdx.z);
        const int w   = (f & 7) * (nwg >> 3) + (f >> 3);
        const int bx  = w % gx;
        const int rst = w / gx;
        do_tile(bx, rst % gy, rst / gy);
    } else {
        // flat 160-block grid, 160 tiles, one per block; XCD k owns works
        // [20k, 20k+20) in x-major (bx, by, n) order.
        const int f   = blockIdx.x;
        const int w   = (f & 7) * 20 + (f >> 3);
        do_tile(w & 3, (w >> 2) & 3, w >> 4);
    }
}

// Per outer step: binp[n] = f16( bb[n] + h[n] + (n==0 ? x_emb : h[n-1]) )
// hhh = f16(0.5*tanh(binp))   (first inner iteration, GEMM-free)
// h is fp16; 8 elements/thread (16B loads/stores).
// XCD mapping matches gemm_bt's 256-row panels: panel id p = 4n + by is
// consumed by gemm works [4p, 4p+4) => consumer XCD = p/5. XCD k produces
// panels [5k, 5k+5); 128 blocks per panel.
__global__ void __launch_bounds__(256)
pre_outer_kernel(const half_t* __restrict__ h,
                 const float* __restrict__ x_emb,
                 const float* __restrict__ bb,   // NB x H (fp32)
                 half_t* __restrict__ binp,
                 half_t* __restrict__ hhh)
{
    const int f  = blockIdx.x;          // 5120 = 8 XCD * 640
    const int k  = f & 7;               // XCD under round-robin dispatch
    const int j  = f >> 3;              // 0..639
    const int p  = 5 * k + (j % 5);     // panel 0..39 (= 4n + by256)
    const int bi = j / 5;               // 0..127: block within panel
    const int n  = p >> 2;

    const size_t idx = ((size_t)p << 18) + (size_t)bi * 2048 + (size_t)threadIdx.x * 8;
    const size_t off = idx - (size_t)n * B_DIM * H_DIM;
    const int    col = (int)(off & (H_DIM - 1));

    const h8vec ha = *(const h8vec*)&h[idx];
    float pv[8];
    if (n == 0) {
        const float4 p0 = *(const float4*)&x_emb[off];
        const float4 p1 = *(const float4*)&x_emb[off + 4];
        pv[0] = p0.x; pv[1] = p0.y; pv[2] = p0.z; pv[3] = p0.w;
        pv[4] = p1.x; pv[5] = p1.y; pv[6] = p1.z; pv[7] = p1.w;
    } else {
        const h8vec pa = *(const h8vec*)&h[idx - (size_t)B_DIM * H_DIM];
#pragma unroll
        for (int j2 = 0; j2 < 8; ++j2) pv[j2] = (float)pa[j2];
    }
    const float4 b0 = *(const float4*)&bb[(size_t)n * H_DIM + col];
    const float4 b1 = *(const float4*)&bb[(size_t)n * H_DIM + col + 4];
    const float bp[8] = {b0.x, b0.y, b0.z, b0.w, b1.x, b1.y, b1.z, b1.w};

    half_t bv[8], hv[8];
#pragma unroll
    for (int j2 = 0; j2 < 8; ++j2) {
        const float biv = (float)ha[j2] + pv[j2] + bp[j2];
        bv[j2] = (half_t)biv;
        hv[j2] = (half_t)(0.5f * fast_tanh(biv));
    }
    *(uint4*)&binp[idx] = *(const uint4*)bv;
    *(uint4*)&hhh[idx]  = *(const uint4*)hv;
}

static inline void conv(const float* src, half_t* dst, int n, hipStream_t s) {
    const int n4 = n / 4;
    f2h_kernel<<<(n4 + 255) / 256, 256, 0, s>>>(src, dst, n4);
}

extern "C" void kernel_launch(void* const* d_in, const int* in_sizes, int n_in,
                              void* d_out, int out_size, void* d_ws, size_t ws_size,
                              hipStream_t stream)
{
    // Inputs/outputs are float32 (reference dtype).
    const float* x     = (const float*)d_in[0];   // B x DIN
    const float* embW  = (const float*)d_in[1];   // H x DIN
    const float* embB  = (const float*)d_in[2];   // H
    const float* blkW  = (const float*)d_in[3];   // NB x H x H
    const float* blkB  = (const float*)d_in[4];   // NB x H
    const float* headW = (const float*)d_in[5];   // DOUT x H
    const float* headB = (const float*)d_in[6];   // DOUT
    float* out = (float*)d_out;                   // B x DOUT

    char* ws = (char*)d_ws;
    size_t off = 0;
    auto alloc = [&](size_t bytes) {
        void* p = ws + off;
        off += (bytes + 255) & ~(size_t)255;
        return p;
    };
    const size_t NE = (size_t)NB * B_DIM * H_DIM;   // 10.5M elements

    // fp32
    float* xemb32 = (float*)alloc((size_t)B_DIM * H_DIM * 4);  // 4 MB
    // fp16 state / weights
    half_t* h16    = (half_t*)alloc(NE * 2);        // 20 MB (outer state h)
    half_t* binp16 = (half_t*)alloc(NE * 2);        // 20 MB (bias+inp)
    half_t* hhh0   = (half_t*)alloc(NE * 2);        // 20 MB
    half_t* hhh1   = (half_t*)alloc(NE * 2);        // 20 MB
    half_t* wx     = (half_t*)alloc((size_t)B_DIM * DIN * 2);
    half_t* wembW  = (half_t*)alloc((size_t)H_DIM * DIN * 2);
    half_t* wblkW  = (half_t*)alloc((size_t)NB * H_DIM * H_DIM * 2); // 20 MB
    half_t* wheadW = (half_t*)alloc((size_t)DOUT * H_DIM * 2);
    (void)ws_size;  // total ~110 MB

    // one-time f32 -> f16 conversion of GEMM operands
    conv(x,     wx,     B_DIM * DIN,        stream);
    conv(embW,  wembW,  H_DIM * DIN,        stream);
    conv(blkW,  wblkW,  NB * H_DIM * H_DIM, stream);
    conv(headW, wheadW, DOUT * H_DIM,       stream);

    hipMemsetAsync(h16, 0, NE * 2, stream);   // h0 = zeros (fp16 +0.0 is 0x0000)

    const dim3 blk(1024);
    const size_t shmem = 131072;   // 128KB dynamic LDS (gfx950: 160KB/CU)

    // x_emb = x @ embed_W^T + embed_b   (fp32 out)
    gemm_bt<0><<<dim3(H_DIM / 256, B_DIM / 256, 1), blk, shmem, stream>>>(
        wx, wembW, embB, nullptr, nullptr, xemb32, nullptr, B_DIM, H_DIM, DIN);

    const int ggrid = 160;                           // 160 tiles, 1 per block/CU
    const int pre_blocks = (int)(NE / (8 * 256));    // 5120
    for (int s = 0; s < STEPS; ++s) {
        // iteration 1 (GEMM-free, hh=0) + binp build
        pre_outer_kernel<<<pre_blocks, dim3(256), 0, stream>>>(h16, xemb32, blkB,
                                                               binp16, hhh0);
        // iterations 2,3,4 (ho read from the fp16 A buffer)
        gemm_bt<1><<<ggrid, blk, shmem, stream>>>(hhh0, wblkW, blkB, binp16, nullptr,
                                                  nullptr, hhh1, B_DIM, H_DIM, H_DIM);
        gemm_bt<1><<<ggrid, blk, shmem, stream>>>(hhh1, wblkW, blkB, binp16, nullptr,
                                                  nullptr, hhh0, B_DIM, H_DIM, H_DIM);
        gemm_bt<1><<<ggrid, blk, shmem, stream>>>(hhh0, wblkW, blkB, binp16, nullptr,
                                                  nullptr, hhh1, B_DIM, H_DIM, H_DIM);
        // iteration 5 fused with outer mix: h = 0.5h + 0.5*(0.5*hh + 0.5*tanh(...))
        gemm_bt<2><<<ggrid, blk, shmem, stream>>>(hhh1, wblkW, blkB, binp16, h16,
                                                  nullptr, h16, B_DIM, H_DIM, H_DIM);
    }

    // out = h[NB-1] @ head_W^T + head_b   (fp32 out; h16 slice fed directly)
    gemm_bt<0><<<dim3(DOUT / 256, B_DIM / 256, 1), blk, shmem, stream>>>(
        h16 + (size_t)(NB - 1) * B_DIM * H_DIM, wheadW, headB, nullptr, nullptr,
        out, nullptr, B_DIM, DOUT, H_DIM);
}

// Round 11
// 4875.664 us; speedup vs baseline: 1.4197x; 1.4197x over previous
//
#include <hip/hip_runtime.h>
#include <cstdint>
#include <cstddef>

// Problem constants (steps=30 is a fixed scalar input — hardcoded for a fixed
// graph-captured launch sequence).
#define B_DIM  1024
#define DIN    512
#define H_DIM  1024
#define DOUT   512
#define NB     10
#define STEPS  30

typedef _Float16 half_t;
typedef __attribute__((ext_vector_type(8))) _Float16 frag_ab;  // 8 fp16 in 4 VGPRs
typedef __attribute__((ext_vector_type(8))) _Float16 h8vec;
typedef __attribute__((ext_vector_type(4))) float    frag_cd;  // 4 fp32 acc

// async global->LDS, 16B per lane; LDS dest is wave-uniform base + lane*16
__device__ __forceinline__ void gload16(const void* g, void* l) {
    __builtin_amdgcn_global_load_lds(
        (const __attribute__((address_space(1))) void*)g,
        (__attribute__((address_space(3))) void*)l, 16, 0, 0);
}

// tanh via hardware exp2/rcp: tanh(x) = 1 - 2/(2^(2*log2e*x) + 1).
// ~5 VALU ops vs ~40-50 for library tanhf; |err| ~1e-6 (<< fp16 rounding);
// saturates correctly; NaN propagates.
__device__ __forceinline__ float fast_tanh(float x) {
    float e, r;
    asm("v_exp_f32 %0, %1" : "=v"(e) : "v"(x * 2.8853900817779268f));
    asm("v_rcp_f32 %0, %1" : "=v"(r) : "v"(e + 1.0f));
    return __builtin_fmaf(-2.0f, r, 1.0f);
}

// f32 -> f16 bulk convert (4 elements/thread)
__global__ void __launch_bounds__(256)
f2h_kernel(const float* __restrict__ src, half_t* __restrict__ dst, int n4)
{
    const int i = blockIdx.x * 256 + threadIdx.x;
    if (i < n4) {
        const float4 v = ((const float4*)src)[i];
        half_t o[4] = { (half_t)v.x, (half_t)v.y, (half_t)v.z, (half_t)v.w };
        ((uint2*)dst)[i] = *(const uint2*)o;
    }
}

// C = A(MxK,f16) @ W(NxK,f16)^T, fp32 acc.
// Round 11 = r9 structure + SPLIT-K WAVES. (r10's 256-tile regressed: 160
// blocks left 96/256 CUs idle — reverted.)
// Tile 128x128, 512 thr / 8 waves, BK=64, dbuf 64KB LDS, 2 blocks/CU
// (16 waves/CU = 4/SIMD). Wave (kh, wm, wn): quadrant (wm,wn) is 64x64,
// computed by TWO waves each handling half of every BK step (kh=0: granules
// 0..3, kh=1: granules 4..7). Per wave-iter: 8 ds_read_b128 for 16 MFMA =
// 0.5 KB/MFMA — r9's 64x32 waves were 0.75 KB/MFMA and LDS-read-BW-bound
// (3.84 MB/CU = 19us floor, 27us observed). Split-K cuts fragment traffic to
// 2.5 MB/CU (~12us floor) at unchanged TLP/LDS/grid. Partial sums reduced
// through fsm in the epilogue (kh=1 spills, kh=0 adds in place).
// Counted-vmcnt pipeline: stage(t+1) [4 loads/wave]; s_waitcnt vmcnt(4);
// barrier; compute(t); barrier.
//
// Grid = 512 blocks = co-resident capacity; 640 tiles; XCD chunk of 80:
// block j does tile j, j<16 also tile 64+j. XCD mapping: n-chunked (XCD k
// owns works [80k,80k+80) x-major => ~1.25 n-slices/XCD; W-slice persists
// in its 4MB L2 across all dispatches).
//
// LDS XOR-swizzle (granule ^= row&7) via pre-swizzled global source
// (global_load_lds dest must stay linear) + matching XOR on fragment reads.
//
// Epilogue: fsm[128][128] f32 (dead staging LDS) with granule swizzle
// gl=(g&24)|((g^(g>>3)^(row&7))&7): kh=1 spill, barrier, kh=0 add, barrier,
// then linear pass (8 contiguous elems/thread, 16B vector loads/stores).
// ho re-read from global A (L2-hot).
//
// MODE 0: out32 = C + bias[col]                         (embed / head)
// MODE 1: out16 = 0.5*A[row,col] + 0.5*tanh(C+binp)     (inner iters 2,3,4; K==N)
// MODE 2: hn = 0.5*A[row,col] + 0.5*tanh(C+binp);
//         out16 = 0.5*aux16 + 0.5*hn   (iter 5 + outer mix; aux16==out16==h16)
template <int MODE>
__global__ void __launch_bounds__(512, 4)
gemm_bt(const half_t* __restrict__ A,
        const half_t* __restrict__ W,
        const float* __restrict__ bias,
        const half_t* __restrict__ binp,
        const half_t* aux16,          // no restrict (aliases out16 in MODE 2)
        float* __restrict__ out32,
        half_t* out16,
        int M, int N, int K)
{
    // 64KB: [0,32K) = lA[2][128*64], [32K,64K) = lB[2][128*64].
    // Epilogue reuses the whole thing as swizzled fsm[128][128] f32.
    __shared__ __attribute__((aligned(16))) char lds_raw[65536];
    half_t* lA  = (half_t*)lds_raw;
    half_t* lB  = (half_t*)(lds_raw + 32768);
    float*  fsm = (float*)lds_raw;

    const int tid  = threadIdx.x;        // 0..511
    const int wave = tid >> 6;           // 0..7
    const int lane = tid & 63;
    const int q    = lane >> 4;          // quad 0..3
    const int r16  = lane & 15;
    const int kh   = wave >> 2;          // 0..1: K-half within each BK step
    const int wm   = (wave >> 1) & 1;    // 0..1: 64-row half
    const int wn   = wave & 1;           // 0..1: 64-col half

    // staging geometry (BK=64): lane i's 16B lands at lds_base + i*16.
    // phys slot (srow, lane&7); global column pre-swizzled so read-side XOR
    // (granule ^ row&7) recovers linear data.
    const int srow = lane >> 3;                     // 0..7 within 8-row chunk
    const int scol = ((lane & 7) ^ srow) * 8;       // swizzled k offset (elements)

    auto do_tile = [&](int bx, int by, int n) {
        const half_t* An = A + (size_t)n * M * K;
        const half_t* Wn = W + (size_t)n * N * K;
        const float*  bn = bias + (size_t)n * N;
        const half_t* binpn = binp;
        const half_t* auxn  = aux16;
        half_t* outn = out16;
        if (MODE != 0) {
            const size_t so = (size_t)n * M * N;
            binpn = binp + so;
            outn  = out16 + so;
            if (MODE == 2) auxn = aux16 + so;
        }
        const int tileM = by * 128;
        const int tileN = bx * 128;

        // per-lane global staging bases; each wave stages 16 rows of lA + lB
        const half_t* gA = An + (size_t)(tileM + wave * 16 + srow) * K + scol;
        const half_t* gW = Wn + (size_t)(tileN + wave * 16 + srow) * K + scol;

        auto stage = [&](int k0, int b) {
#pragma unroll
            for (int i = 0; i < 2; ++i) {
                gload16(gA + (size_t)i * 8 * K + k0,
                        (void*)&lA[b * 8192 + (wave * 16 + i * 8) * 64]);
                gload16(gW + (size_t)i * 8 * K + k0,
                        (void*)&lB[b * 8192 + (wave * 16 + i * 8) * 64]);
            }
        };

        frag_cd acc[4][4];
#pragma unroll
        for (int mt = 0; mt < 4; ++mt)
#pragma unroll
            for (int nt = 0; nt < 4; ++nt)
                acc[mt][nt] = (frag_cd){0.f, 0.f, 0.f, 0.f};

        __syncthreads();   // previous rep's fsm reads done before restaging
        const int NT = K >> 6;
        stage(0, 0);       // 4 loads/wave in flight

        // this wave's K-half granule (swizzled per row)
        int cur = 0;
        for (int t = 0; t < NT; ++t) {
            // prefetch next tile, then wait ONLY for tile t's 4 loads:
            // vmcnt counts in-order retirement; <=4 outstanding => 4 oldest done.
            if (t + 1 < NT) {
                stage((t + 1) << 6, cur ^ 1);                       // 8 in flight
                asm volatile("s_waitcnt vmcnt(4)" ::: "memory");    // t landed
            } else {
                asm volatile("s_waitcnt vmcnt(0)" ::: "memory");    // final tile
            }
            __builtin_amdgcn_s_barrier();   // all waves: buf[cur] resident
            asm volatile("" ::: "memory");

            const int cb = ((kh * 4 + q) ^ (r16 & 7)) * 8;   // swizzled granule
            frag_ab av[4], bv[4];
#pragma unroll
            for (int mt = 0; mt < 4; ++mt)
                av[mt] = *(const frag_ab*)&lA[cur * 8192 + (wm * 64 + mt * 16 + r16) * 64 + cb];
#pragma unroll
            for (int nt = 0; nt < 4; ++nt)
                bv[nt] = *(const frag_ab*)&lB[cur * 8192 + (wn * 64 + nt * 16 + r16) * 64 + cb];
#pragma unroll
            for (int mt = 0; mt < 4; ++mt)
#pragma unroll
                for (int nt = 0; nt < 4; ++nt)
                    acc[mt][nt] = __builtin_amdgcn_mfma_f32_16x16x32_f16(
                        av[mt], bv[nt], acc[mt][nt], 0, 0, 0);

            asm volatile("" ::: "memory");
            __builtin_amdgcn_s_barrier();   // buf[cur] free for overwrite
            cur ^= 1;
        }

        // ---- epilogue: split-K reduction through fsm, then linear pass ----
        // C/D layout: col = lane&15, row = quad*4 + reg.
        // phase 1a: kh==1 waves spill their partials (staging LDS is dead)
        if (kh == 1) {
#pragma unroll
            for (int mt = 0; mt < 4; ++mt)
#pragma unroll
                for (int nt = 0; nt < 4; ++nt)
#pragma unroll
                    for (int r = 0; r < 4; ++r) {
                        const int row = wm * 64 + mt * 16 + q * 4 + r;
                        const int col = wn * 64 + nt * 16 + r16;
                        const int g   = col >> 2;
                        const int gl  = (g & 24) | ((g ^ (g >> 3) ^ (row & 7)) & 7);
                        fsm[row * 128 + gl * 4 + (col & 3)] = acc[mt][nt][r];
                    }
        }
        __syncthreads();
        // phase 1b: kh==0 waves add theirs in place
        if (kh == 0) {
#pragma unroll
            for (int mt = 0; mt < 4; ++mt)
#pragma unroll
                for (int nt = 0; nt < 4; ++nt)
#pragma unroll
                    for (int r = 0; r < 4; ++r) {
                        const int row = wm * 64 + mt * 16 + q * 4 + r;
                        const int col = wn * 64 + nt * 16 + r16;
                        const int g   = col >> 2;
                        const int gl  = (g & 24) | ((g ^ (g >> 3) ^ (row & 7)) & 7);
                        fsm[row * 128 + gl * 4 + (col & 3)] += acc[mt][nt][r];
                    }
        }
        __syncthreads();

        // phase 2: linear vectorized — 8 contiguous elements/thread, 4 rounds
#pragma unroll
        for (int c = 0; c < 4; ++c) {
            const int e   = (c * 512 + tid) * 8;     // elem idx in 128x128 tile
            const int rl  = e >> 7;
            const int cl  = e & 127;
            const int row = tileM + rl;
            const int col = tileN + cl;
            const size_t gidx = (size_t)row * N + col;

            const int g0  = cl >> 2;
            const int gl0 = (g0 & 24) | ((g0 ^ (g0 >> 3) ^ (rl & 7)) & 7);
            const int g1  = g0 + 1;
            const int gl1 = (g1 & 24) | ((g1 ^ (g1 >> 3) ^ (rl & 7)) & 7);
            const float4 va = *(const float4*)&fsm[rl * 128 + gl0 * 4];
            const float4 vb = *(const float4*)&fsm[rl * 128 + gl1 * 4];
            const float vv[8] = {va.x, va.y, va.z, va.w, vb.x, vb.y, vb.z, vb.w};

            if (MODE == 0) {
                const float4 b0 = *(const float4*)&bn[col];
                const float4 b1 = *(const float4*)&bn[col + 4];
                float4 o0 = {vv[0] + b0.x, vv[1] + b0.y, vv[2] + b0.z, vv[3] + b0.w};
                float4 o1 = {vv[4] + b1.x, vv[5] + b1.y, vv[6] + b1.z, vv[7] + b1.w};
                *(float4*)&out32[gidx]     = o0;
                *(float4*)&out32[gidx + 4] = o1;
            } else {
                const h8vec bi8 = *(const h8vec*)&binpn[gidx];
                h8vec ho8, ax8;
                ho8 = *(const h8vec*)&An[(size_t)row * K + col];
                if (MODE == 2) ax8 = *(const h8vec*)&auxn[gidx];

                half_t o[8];
#pragma unroll
                for (int j = 0; j < 8; ++j) {
                    const float bi = (float)bi8[j];
                    const float tt = fast_tanh(vv[j] + bi);
                    const float ho = (float)ho8[j];
                    const float hn = 0.5f * ho + 0.5f * tt;
                    const float ov = (MODE == 2) ? 0.5f * (float)ax8[j] + 0.5f * hn : hn;
                    o[j] = (half_t)ov;
                }
                *(uint4*)&outn[gidx] = *(const uint4*)o;
            }
        }
    };

    if (MODE == 0) {
        // small dispatches (embed/head): bijective n-chunked swizzle on dim3 grid
        const int gx  = gridDim.x, gy = gridDim.y;
        const int nwg = gx * gy * gridDim.z;     // divisible by 8 here
        const int f   = blockIdx.x + gx * (blockIdx.y + gy * blockIdx.z);
        const int w   = (f & 7) * (nwg >> 3) + (f >> 3);
        const int bx  = w % gx;
        const int rst = w / gx;
        do_tile(bx, rst % gy, rst / gy);
    } else {
        // flat 512-block grid; 640 tiles; XCD chunk = 80 tiles; block j of an
        // XCD does tile j, and j<16 also tile 64+j (second serial rep).
        const int f   = blockIdx.x;
        const int xcd = f & 7;
        const int j   = f >> 3;
        const int w1  = xcd * 80 + j;
        do_tile(w1 & 7, (w1 >> 3) & 7, w1 >> 6);
        if (j < 16) {
            const int w2 = xcd * 80 + 64 + j;
            do_tile(w2 & 7, (w2 >> 3) & 7, w2 >> 6);
        }
    }
}

// Per outer step: binp[n] = f16( bb[n] + h[n] + (n==0 ? x_emb : h[n-1]) )
// hhh = f16(0.5*tanh(binp))   (first inner iteration, GEMM-free)
// h is fp16; 8 elements/thread (16B loads/stores).
// XCD mapping matches gemm_bt's n-chunking: gemm XCD k reads panels
// [10k, 10k+10) => XCD k produces panels [10k, 10k+10).
__global__ void __launch_bounds__(256)
pre_outer_kernel(const half_t* __restrict__ h,
                 const float* __restrict__ x_emb,
                 const float* __restrict__ bb,   // NB x H (fp32)
                 half_t* __restrict__ binp,
                 half_t* __restrict__ hhh)
{
    const int f  = blockIdx.x;          // 5120 = 8 XCD * 640
    const int k  = f & 7;               // XCD under round-robin dispatch
    const int j  = f >> 3;              // 0..639
    const int p  = 10 * k + (j % 10);   // panel 0..79 (= n*8 + by)
    const int bi = j / 10;              // 0..63: block within panel
    const int n  = p >> 3;

    const size_t idx = ((size_t)p << 17) + (size_t)bi * 2048 + (size_t)threadIdx.x * 8;
    const size_t off = idx - (size_t)n * B_DIM * H_DIM;
    const int    col = (int)(off & (H_DIM - 1));

    const h8vec ha = *(const h8vec*)&h[idx];
    float pv[8];
    if (n == 0) {
        const float4 p0 = *(const float4*)&x_emb[off];
        const float4 p1 = *(const float4*)&x_emb[off + 4];
        pv[0] = p0.x; pv[1] = p0.y; pv[2] = p0.z; pv[3] = p0.w;
        pv[4] = p1.x; pv[5] = p1.y; pv[6] = p1.z; pv[7] = p1.w;
    } else {
        const h8vec pa = *(const h8vec*)&h[idx - (size_t)B_DIM * H_DIM];
#pragma unroll
        for (int j2 = 0; j2 < 8; ++j2) pv[j2] = (float)pa[j2];
    }
    const float4 b0 = *(const float4*)&bb[(size_t)n * H_DIM + col];
    const float4 b1 = *(const float4*)&bb[(size_t)n * H_DIM + col + 4];
    const float bp[8] = {b0.x, b0.y, b0.z, b0.w, b1.x, b1.y, b1.z, b1.w};

    half_t bv[8], hv[8];
#pragma unroll
    for (int j2 = 0; j2 < 8; ++j2) {
        const float biv = (float)ha[j2] + pv[j2] + bp[j2];
        bv[j2] = (half_t)biv;
        hv[j2] = (half_t)(0.5f * fast_tanh(biv));
    }
    *(uint4*)&binp[idx] = *(const uint4*)bv;
    *(uint4*)&hhh[idx]  = *(const uint4*)hv;
}

static inline void conv(const float* src, half_t* dst, int n, hipStream_t s) {
    const int n4 = n / 4;
    f2h_kernel<<<(n4 + 255) / 256, 256, 0, s>>>(src, dst, n4);
}

extern "C" void kernel_launch(void* const* d_in, const int* in_sizes, int n_in,
                              void* d_out, int out_size, void* d_ws, size_t ws_size,
                              hipStream_t stream)
{
    // Inputs/outputs are float32 (reference dtype).
    const float* x     = (const float*)d_in[0];   // B x DIN
    const float* embW  = (const float*)d_in[1];   // H x DIN
    const float* embB  = (const float*)d_in[2];   // H
    const float* blkW  = (const float*)d_in[3];   // NB x H x H
    const float* blkB  = (const float*)d_in[4];   // NB x H
    const float* headW = (const float*)d_in[5];   // DOUT x H
    const float* headB = (const float*)d_in[6];   // DOUT
    float* out = (float*)d_out;                   // B x DOUT

    char* ws = (char*)d_ws;
    size_t off = 0;
    auto alloc = [&](size_t bytes) {
        void* p = ws + off;
        off += (bytes + 255) & ~(size_t)255;
        return p;
    };
    const size_t NE = (size_t)NB * B_DIM * H_DIM;   // 10.5M elements

    // fp32
    float* xemb32 = (float*)alloc((size_t)B_DIM * H_DIM * 4);  // 4 MB
    // fp16 state / weights
    half_t* h16    = (half_t*)alloc(NE * 2);        // 20 MB (outer state h)
    half_t* binp16 = (half_t*)alloc(NE * 2);        // 20 MB (bias+inp)
    half_t* hhh0   = (half_t*)alloc(NE * 2);        // 20 MB
    half_t* hhh1   = (half_t*)alloc(NE * 2);        // 20 MB
    half_t* wx     = (half_t*)alloc((size_t)B_DIM * DIN * 2);
    half_t* wembW  = (half_t*)alloc((size_t)H_DIM * DIN * 2);
    half_t* wblkW  = (half_t*)alloc((size_t)NB * H_DIM * H_DIM * 2); // 20 MB
    half_t* wheadW = (half_t*)alloc((size_t)DOUT * H_DIM * 2);
    (void)ws_size;  // total ~110 MB

    // one-time f32 -> f16 conversion of GEMM operands
    conv(x,     wx,     B_DIM * DIN,        stream);
    conv(embW,  wembW,  H_DIM * DIN,        stream);
    conv(blkW,  wblkW,  NB * H_DIM * H_DIM, stream);
    conv(headW, wheadW, DOUT * H_DIM,       stream);

    hipMemsetAsync(h16, 0, NE * 2, stream);   // h0 = zeros (fp16 +0.0 is 0x0000)

    const dim3 blk(512);

    // x_emb = x @ embed_W^T + embed_b   (fp32 out)
    gemm_bt<0><<<dim3(H_DIM / 128, B_DIM / 128, 1), blk, 0, stream>>>(
        wx, wembW, embB, nullptr, nullptr, xemb32, nullptr, B_DIM, H_DIM, DIN);

    const int ggrid = 512;                           // = co-resident capacity
    const int pre_blocks = (int)(NE / (8 * 256));    // 5120
    for (int s = 0; s < STEPS; ++s) {
        // iteration 1 (GEMM-free, hh=0) + binp build
        pre_outer_kernel<<<pre_blocks, dim3(256), 0, stream>>>(h16, xemb32, blkB,
                                                               binp16, hhh0);
        // iterations 2,3,4 (ho read from the fp16 A buffer)
        gemm_bt<1><<<ggrid, blk, 0, stream>>>(hhh0, wblkW, blkB, binp16, nullptr,
                                              nullptr, hhh1, B_DIM, H_DIM, H_DIM);
        gemm_bt<1><<<ggrid, blk, 0, stream>>>(hhh1, wblkW, blkB, binp16, nullptr,
                                              nullptr, hhh0, B_DIM, H_DIM, H_DIM);
        gemm_bt<1><<<ggrid, blk, 0, stream>>>(hhh0, wblkW, blkB, binp16, nullptr,
                                              nullptr, hhh1, B_DIM, H_DIM, H_DIM);
        // iteration 5 fused with outer mix: h = 0.5h + 0.5*(0.5*hh + 0.5*tanh(...))
        gemm_bt<2><<<ggrid, blk, 0, stream>>>(hhh1, wblkW, blkB, binp16, h16,
                                              nullptr, h16, B_DIM, H_DIM, H_DIM);
    }

    // out = h[NB-1] @ head_W^T + head_b   (fp32 out; h16 slice fed directly)
    gemm_bt<0><<<dim3(DOUT / 128, B_DIM / 128, 1), blk, 0, stream>>>(
        h16 + (size_t)(NB - 1) * B_DIM * H_DIM, wheadW, headB, nullptr, nullptr,
        out, nullptr, B_DIM, DOUT, H_DIM);
}